// Round 1
// baseline (15399.405 us; speedup 1.0000x reference)
//
#include <hip/hip_runtime.h>
#include <hip/hip_bf16.h>
#include <math.h>

// Problem constants (match reference)
constexpr int B = 4, S = 2048, E = 1024, H = 16, D = 64;
constexpr int QT = 64;           // query rows per block
constexpr int KT = 64;           // key rows per tile
constexpr float NEG = -1000000000.0f;
constexpr float SCALE = 0.125f;  // 1/sqrt(64)

// LDS row strides (floats). +4 keeps float4 alignment and rotates banks by 4
// per row -> all hot read patterns are <=2-way (free on gfx950, m136).
constexpr int LD = D + 4;   // 68

// LDS budget: 3 buffers * 64*68*4 B = 52,224 B -> 3 blocks/CU.
// KPs holds the K tile during scores, then is reused for P during PV.
__global__ __launch_bounds__(256, 3)
void fa_fp32(const float* __restrict__ Q, const float* __restrict__ K,
             const float* __restrict__ V, const int* __restrict__ M,
             float* __restrict__ O)
{
    __shared__ float Qs[QT][LD];
    __shared__ float Vs[KT][LD];
    __shared__ float KPs[KT][LD];   // K tile, then P tile

    const int tid = threadIdx.x;
    const int tx  = tid & 15;       // 0..15
    const int ty  = tid >> 4;       // 0..15

    // Grid order: 16 heads of same (b, q-tile) adjacent -> mask tiles hit L2.
    const int bid = blockIdx.x;
    const int h   = bid % H;
    const int b   = (bid / H) % B;
    const int qt  = bid / (H * B);
    const int q0  = qt * QT;

    // ---- load Q tile (QT x D), coalesced float4 ----
    {
        const int col = tx * 4;
#pragma unroll
        for (int i = 0; i < 4; ++i) {
            const int row = ty + i * 16;
            const float4 t = *(const float4*)&Q[((size_t)(b * S + q0 + row)) * E + h * D + col];
            *(float4*)&Qs[row][col] = t;
        }
    }

    // Per-thread state: 4 query rows (qr0..qr0+3), 4 output dims (d0..d0+3).
    const int qr0 = ty * 4;
    const int d0  = tx * 4;

    float acc[4][4] = {};
    float m_i[4], l_i[4];
#pragma unroll
    for (int j = 0; j < 4; ++j) { m_i[j] = -INFINITY; l_i[j] = 0.0f; }

    for (int kt = 0; kt < S; kt += KT) {
        __syncthreads();  // A: previous PV (reads KPs-as-P, Vs) done

        // ---- stage K and V tiles, coalesced float4 ----
        {
            const int col = tx * 4;
#pragma unroll
            for (int i = 0; i < 4; ++i) {
                const int row = ty + i * 16;
                const size_t g = ((size_t)(b * S + kt + row)) * E + h * D + col;
                *(float4*)&KPs[row][col] = *(const float4*)&K[g];
                *(float4*)&Vs[row][col]  = *(const float4*)&V[g];
            }
        }
        __syncthreads();  // B: tiles visible

        // ---- scores: 4q x 4k micro-tile; keys k_i = tx + 16*i (strided to
        //      keep Ks reads 2-way max) ----
        float s[4][4] = {};
#pragma unroll
        for (int d = 0; d < D; d += 4) {
            float4 a[4], bb[4];
#pragma unroll
            for (int j = 0; j < 4; ++j) a[j] = *(const float4*)&Qs[qr0 + j][d];
#pragma unroll
            for (int i = 0; i < 4; ++i) bb[i] = *(const float4*)&KPs[tx + 16 * i][d];
#pragma unroll
            for (int j = 0; j < 4; ++j)
#pragma unroll
                for (int i = 0; i < 4; ++i)
                    s[j][i] += a[j].x * bb[i].x + a[j].y * bb[i].y +
                               a[j].z * bb[i].z + a[j].w * bb[i].w;
        }

        // ---- mask + scale (reference: masked -> NEG, then plain softmax) ----
#pragma unroll
        for (int j = 0; j < 4; ++j) {
            const int* mrow = &M[((size_t)b * S + (q0 + qr0 + j)) * S + kt];
#pragma unroll
            for (int i = 0; i < 4; ++i) {
                const int mk = mrow[tx + 16 * i];
                s[j][i] = mk ? s[j][i] * SCALE : NEG;
            }
        }

        // ---- online softmax (row = 16 consecutive lanes, shfl_xor w=16) ----
#pragma unroll
        for (int j = 0; j < 4; ++j) {
            float tm = fmaxf(fmaxf(s[j][0], s[j][1]), fmaxf(s[j][2], s[j][3]));
#pragma unroll
            for (int off = 8; off; off >>= 1)
                tm = fmaxf(tm, __shfl_xor(tm, off, 16));
            const float nm    = fmaxf(m_i[j], tm);
            const float alpha = __expf(m_i[j] - nm);   // exp(-inf)=0 first tile
            m_i[j] = nm;
            float rs = 0.0f;
#pragma unroll
            for (int i = 0; i < 4; ++i) {
                const float p = __expf(s[j][i] - nm);  // masked: exp(NEG-nm)=0
                s[j][i] = p;
                rs += p;
            }
#pragma unroll
            for (int off = 8; off; off >>= 1)
                rs += __shfl_xor(rs, off, 16);
            l_i[j] = l_i[j] * alpha + rs;
#pragma unroll
            for (int dd = 0; dd < 4; ++dd) acc[j][dd] *= alpha;
        }

        __syncthreads();  // C: all waves done reading K tile

        // ---- write P into KPs (scalar writes, 2-way max by construction) ----
#pragma unroll
        for (int j = 0; j < 4; ++j)
#pragma unroll
            for (int i = 0; i < 4; ++i)
                KPs[qr0 + j][tx + 16 * i] = s[j][i];

        __syncthreads();  // D: P visible

        // ---- O += P * V : 4q x 4d micro-tile, k unrolled by 4 ----
#pragma unroll 4
        for (int kk = 0; kk < KT; kk += 4) {
            float4 p[4], vv[4];
#pragma unroll
            for (int j = 0; j < 4; ++j) p[j] = *(const float4*)&KPs[qr0 + j][kk];
#pragma unroll
            for (int u = 0; u < 4; ++u) vv[u] = *(const float4*)&Vs[kk + u][d0];
#pragma unroll
            for (int j = 0; j < 4; ++j) {
                acc[j][0] += p[j].x * vv[0].x + p[j].y * vv[1].x + p[j].z * vv[2].x + p[j].w * vv[3].x;
                acc[j][1] += p[j].x * vv[0].y + p[j].y * vv[1].y + p[j].z * vv[2].y + p[j].w * vv[3].y;
                acc[j][2] += p[j].x * vv[0].z + p[j].y * vv[1].z + p[j].z * vv[2].z + p[j].w * vv[3].z;
                acc[j][3] += p[j].x * vv[0].w + p[j].y * vv[1].w + p[j].z * vv[2].w + p[j].w * vv[3].w;
            }
        }
    }

    // ---- epilogue: normalize and store (coalesced float4) ----
#pragma unroll
    for (int j = 0; j < 4; ++j) {
        const float inv = 1.0f / l_i[j];
        float4 r;
        r.x = acc[j][0] * inv;
        r.y = acc[j][1] * inv;
        r.z = acc[j][2] * inv;
        r.w = acc[j][3] * inv;
        *(float4*)&O[((size_t)(b * S + q0 + qr0 + j)) * E + h * D + d0] = r;
    }
}

extern "C" void kernel_launch(void* const* d_in, const int* in_sizes, int n_in,
                              void* d_out, int out_size, void* d_ws, size_t ws_size,
                              hipStream_t stream) {
    (void)in_sizes; (void)n_in; (void)out_size; (void)d_ws; (void)ws_size;
    const float* q = (const float*)d_in[0];
    const float* k = (const float*)d_in[1];
    const float* v = (const float*)d_in[2];
    const int*   m = (const int*)d_in[3];
    float* out = (float*)d_out;

    const dim3 grid(B * H * (S / QT));   // 2048 blocks
    fa_fp32<<<grid, 256, 0, stream>>>(q, k, v, m, out);
}

// Round 2
// 309.523 us; speedup vs baseline: 49.7521x; 49.7521x over previous
//
#include <hip/hip_runtime.h>
#include <hip/hip_bf16.h>
#include <math.h>

// Problem constants (match reference)
constexpr int B = 4, S = 2048, E = 1024, H = 16, D = 64;
constexpr float NEGF = -1000000000.0f;

typedef __attribute__((ext_vector_type(8))) short short8;   // 8 bf16 = 4 VGPRs
typedef __attribute__((ext_vector_type(16))) float f32x16;  // MFMA 32x32 C/D

// ---------------- helpers ----------------
__device__ inline short f2bf(float x) {
    __hip_bfloat16 h = __float2bfloat16(x);
    return *reinterpret_cast<short*>(&h);
}
__device__ inline unsigned pk(float a, float b) {
    return (unsigned)(unsigned short)f2bf(a) | ((unsigned)(unsigned short)f2bf(b) << 16);
}
__device__ inline void gl_lds16(const void* g, void* l) {
    __builtin_amdgcn_global_load_lds(
        (const __attribute__((address_space(1))) unsigned int*)g,
        (__attribute__((address_space(3))) unsigned int*)l, 16, 0, 0);
}

// ws layout (bytes):
//   Qws  [bh][s][72 bf16]          @ 0          18,874,368
//   Kws  [bh][s][72 bf16]          @ 18874368   18,874,368
//   Vtws [bh][kt][64 d][72 bf16]   @ 37748736   18,874,368  (per-tile chunked)
//   Mb   [b][q][32 u64]            @ 56623104    2,097,152
constexpr size_t WS_Q  = 0;
constexpr size_t WS_K  = 18874368;
constexpr size_t WS_VT = 37748736;
constexpr size_t WS_MB = 56623104;
constexpr size_t WS_NEED = 58720256;

// ---------------- pre-pass 1: Q/K -> padded head-major bf16 ----------------
// dst row = (b*H+h)*S + s, 72 bf16 (144 B) per row, cols 64..71 = junk pad.
__global__ void cvt_qk(const float* __restrict__ src, char* __restrict__ dst, float scale) {
    int g = blockIdx.x * 256 + threadIdx.x;       // 524288 threads
    int rowd = g >> 2, qtr = g & 3;
    int b = rowd >> 15, h = (rowd >> 11) & 15, s = rowd & 2047;
    const float* p = src + ((size_t)(b * S + s)) * E + h * 64 + qtr * 16;
    float4 v0 = *(const float4*)(p + 0),  v1 = *(const float4*)(p + 4);
    float4 v2 = *(const float4*)(p + 8),  v3 = *(const float4*)(p + 12);
    uint4 o0, o1;
    o0.x = pk(v0.x * scale, v0.y * scale); o0.y = pk(v0.z * scale, v0.w * scale);
    o0.z = pk(v1.x * scale, v1.y * scale); o0.w = pk(v1.z * scale, v1.w * scale);
    o1.x = pk(v2.x * scale, v2.y * scale); o1.y = pk(v2.z * scale, v2.w * scale);
    o1.z = pk(v3.x * scale, v3.y * scale); o1.w = pk(v3.z * scale, v3.w * scale);
    char* d = dst + (size_t)rowd * 144 + qtr * 32;
    *(uint4*)d = o0; *(uint4*)(d + 16) = o1;
}

// ---------------- pre-pass 2: V -> per-tile transposed bf16 ----------------
// out tile (bh,kt): 64 rows (d) x 72 bf16 (cols = key-local 0..63, pad junk)
__global__ void vtrans(const float* __restrict__ V, char* __restrict__ dst) {
    __shared__ float Vf[64][69];
    int t = threadIdx.x;
    int bh = blockIdx.x >> 5, kt = blockIdx.x & 31;
    int b = bh >> 4, h = bh & 15;
    {
        int r = t >> 2, c4 = (t & 3) * 16;
        const float* p = V + ((size_t)(b * S + kt * 64 + r)) * E + h * 64 + c4;
        float4 a = *(const float4*)(p + 0), bb = *(const float4*)(p + 4);
        float4 c = *(const float4*)(p + 8), dd = *(const float4*)(p + 12);
        *(float4*)&Vf[r][c4 + 0] = a;  *(float4*)&Vf[r][c4 + 4] = bb;
        *(float4*)&Vf[r][c4 + 8] = c;  *(float4*)&Vf[r][c4 + 12] = dd;
    }
    __syncthreads();
    int d = t >> 2, sq = (t & 3) * 16;
    float v[16];
#pragma unroll
    for (int i = 0; i < 16; ++i) v[i] = Vf[sq + i][d];
    uint4 o0, o1;
    o0.x = pk(v[0], v[1]);  o0.y = pk(v[2], v[3]);
    o0.z = pk(v[4], v[5]);  o0.w = pk(v[6], v[7]);
    o1.x = pk(v[8], v[9]);  o1.y = pk(v[10], v[11]);
    o1.z = pk(v[12], v[13]); o1.w = pk(v[14], v[15]);
    char* o = dst + ((size_t)(bh * 32 + kt)) * 9216 + d * 144 + sq * 2;
    *(uint4*)o = o0; *(uint4*)(o + 16) = o1;
}

// ---------------- pre-pass 3: mask -> bitmask ----------------
// Mb word idx = (b*S+q)*32 + kt64 ; bit k = (mask != 0) for key kt64*64+k
__global__ void maskbits(const int* __restrict__ M, unsigned long long* __restrict__ Mb) {
    int lane = threadIdx.x & 63;
    int gw = blockIdx.x * 4 + (threadIdx.x >> 6);
#pragma unroll
    for (int r = 0; r < 8; ++r) {
        size_t word = (size_t)gw * 8 + r;
        int m = M[word * 64 + lane];
        unsigned long long bal = __ballot(m != 0);
        if (lane == 0) Mb[word] = bal;
    }
}

// ---------------- main: fused attention, transposed-world MFMA ----------------
// Block: 256 thr = 4 waves; wave owns 64 q (2 nb-blocks of 32). QT=256/block.
// Per k-tile (64 keys): S^T = K(64x64d) * Q^T -> softmax (no-max streaming)
// -> P bf16 to LDS -> O^T += V^T * P^T.  Epilogue: /l, LDS-transpose, store.
__global__ __launch_bounds__(256, 2)
void fa_mfma(const char* __restrict__ ws, const unsigned long long* __restrict__ Mb,
             float* __restrict__ O) {
    // LDS: Ks [0,9216) | Vt [9216,18432) | Ps 4 x 9216 per wave [18432,55296)
    __shared__ char smem[55296];
    const int tid = threadIdx.x;
    const int w = tid >> 6, lane = tid & 63;
    const int L5 = lane & 31, h6 = lane >> 5;
    const int sh4 = h6 * 4;
    const int h = blockIdx.x & 15, b = (blockIdx.x >> 4) & 3, qt = blockIdx.x >> 6;
    const int bh = b * 16 + h;
    const int q0w = qt * 256 + w * 64;            // wave's q base
    char* const Ps = smem + 18432 + w * 9216;     // wave-private

    const char* Qws = ws + WS_Q;
    const char* Kws = ws + WS_K;
    const char* Vtws = ws + WS_VT;

    // ---- stage wave's Q band (9216 B contiguous) into Ps, read B-frags ----
    {
        const char* qsrc = Qws + ((size_t)bh * S + q0w) * 144;
#pragma unroll
        for (int c = 0; c < 9; ++c)
            gl_lds16(qsrc + c * 1024 + lane * 16, Ps + c * 1024);
    }
    __syncthreads();   // drains vmcnt -> Q visible
    short8 qf[2][4];
#pragma unroll
    for (int nb = 0; nb < 2; ++nb)
#pragma unroll
        for (int ks = 0; ks < 4; ++ks)
            qf[nb][ks] = *(const short8*)(Ps + (nb * 32 + L5) * 144 + ks * 32 + h6 * 16);

    f32x16 acc[2][2];
#pragma unroll
    for (int mb = 0; mb < 2; ++mb)
#pragma unroll
        for (int nb = 0; nb < 2; ++nb) acc[mb][nb] = (f32x16)0.0f;
    float l0 = 0.0f, l1 = 0.0f;

    const int qA = q0w + L5, qB = qA + 32;

    for (int kt = 0; kt < S; kt += 64) {
        const int kti = kt >> 6;
        // prefetch mask bitwords (2 MB dataset, L2-resident)
        const unsigned long long mA = Mb[((size_t)b * S + qA) * 32 + kti];
        const unsigned long long mB = Mb[((size_t)b * S + qB) * 32 + kti];

        __syncthreads();   // everyone done reading previous Ks/Vt
        {   // stage K tile (9216) + Vt tile (9216): pure linear async copy
            const char* ksrc = Kws + ((size_t)bh * S + kt) * 144;
            const char* vsrc = Vtws + ((size_t)bh * 32 + kti) * 9216;
#pragma unroll
            for (int c = 0; c < 5; ++c) {
                int idx = c * 4 + w;
                if (idx < 18) {
                    int off = idx * 1024;
                    const char* g = (off < 9216) ? (ksrc + off) : (vsrc + off - 9216);
                    gl_lds16(g + lane * 16, smem + off);
                }
            }
        }
        __syncthreads();   // tiles visible

        // ---- scores S^T (key x q) + streaming softmax + P store ----
#pragma unroll
        for (int mb = 0; mb < 2; ++mb) {
            short8 kf[4];
#pragma unroll
            for (int ks = 0; ks < 4; ++ks)
                kf[ks] = *(const short8*)(smem + (mb * 32 + L5) * 144 + ks * 32 + h6 * 16);
            const unsigned wmA = (unsigned)(mA >> (mb * 32)) >> sh4;
            const unsigned wmB = (unsigned)(mB >> (mb * 32)) >> sh4;
#pragma unroll
            for (int nb = 0; nb < 2; ++nb) {
                f32x16 s = (f32x16)0.0f;
#pragma unroll
                for (int ks = 0; ks < 4; ++ks)
                    s = __builtin_amdgcn_mfma_f32_32x32x16_bf16(kf[ks], qf[nb][ks], s, 0, 0, 0);
                const unsigned wm = nb ? wmB : wmA;
                float p[16], lacc = 0.0f;
#pragma unroll
                for (int r = 0; r < 16; ++r) {
                    const int kc = (r & 3) + 8 * (r >> 2);   // + 4*h6 handled by sh4
                    float sv = ((wm >> kc) & 1u) ? s[r] : NEGF;
                    p[r] = __expf(sv);                        // masked -> exact 0
                    lacc += p[r];
                }
                if (nb) l1 += lacc; else l0 += lacc;
                char* prow = Ps + (nb * 32 + L5) * 144 + mb * 64 + h6 * 8;
#pragma unroll
                for (int g4 = 0; g4 < 4; ++g4) {
                    short4 t;
                    t.x = f2bf(p[4 * g4 + 0]); t.y = f2bf(p[4 * g4 + 1]);
                    t.z = f2bf(p[4 * g4 + 2]); t.w = f2bf(p[4 * g4 + 3]);
                    *(short4*)(prow + g4 * 16) = t;
                }
            }
        }

        // wave-private P just written; drain LDS before fragment reads
        __builtin_amdgcn_s_waitcnt(0xc07f);   // lgkmcnt(0)

        // ---- O^T += V^T * P^T ----
        short8 pf[2][4];
#pragma unroll
        for (int nb = 0; nb < 2; ++nb)
#pragma unroll
            for (int ks = 0; ks < 4; ++ks)
                pf[nb][ks] = *(const short8*)(Ps + (nb * 32 + L5) * 144 + ks * 32 + h6 * 16);
#pragma unroll
        for (int mb = 0; mb < 2; ++mb) {
            short8 vf[4];
#pragma unroll
            for (int ks = 0; ks < 4; ++ks)
                vf[ks] = *(const short8*)(smem + 9216 + (mb * 32 + L5) * 144 + ks * 32 + h6 * 16);
#pragma unroll
            for (int nb = 0; nb < 2; ++nb)
#pragma unroll
                for (int ks = 0; ks < 4; ++ks)
                    acc[mb][nb] = __builtin_amdgcn_mfma_f32_32x32x16_bf16(vf[ks], pf[nb][ks], acc[mb][nb], 0, 0, 0);
        }
    }

    // ---- epilogue ----
    l0 += __shfl_xor(l0, 32);
    l1 += __shfl_xor(l1, 32);
    const float inv[2] = {1.0f / l0, 1.0f / l1};
    __syncthreads();   // done with Ks/Vt/P everywhere; reuse Ps area as fp32 tile
#pragma unroll
    for (int nb = 0; nb < 2; ++nb) {
        // write 32q x 64d fp32 (stride 68 dwords) into wave-private Ps area
#pragma unroll
        for (int mb = 0; mb < 2; ++mb)
#pragma unroll
            for (int g4 = 0; g4 < 4; ++g4) {
                float4 t;
                t.x = acc[mb][nb][g4 * 4 + 0] * inv[nb];
                t.y = acc[mb][nb][g4 * 4 + 1] * inv[nb];
                t.z = acc[mb][nb][g4 * 4 + 2] * inv[nb];
                t.w = acc[mb][nb][g4 * 4 + 3] * inv[nb];
                *(float4*)(Ps + (L5 * 68 + mb * 32 + g4 * 8 + h6 * 4) * 4) = t;
            }
        __builtin_amdgcn_s_waitcnt(0xc07f);   // lgkmcnt(0): wave-internal ordering
        const int r16 = lane >> 4, dc = lane & 15;
#pragma unroll
        for (int i = 0; i < 8; ++i) {
            const int row = i * 4 + r16;
            float4 t = *(const float4*)(Ps + (row * 68 + dc * 4) * 4);
            *(float4*)(O + ((size_t)b * S + q0w + nb * 32 + row) * E + h * 64 + dc * 4) = t;
        }
        __builtin_amdgcn_s_waitcnt(0xc07f);   // reads done before nb=1 overwrites
    }
}

// ---------------- fallback (round-1 fp32 kernel, known-correct) ----------------
constexpr int QT = 64, KT = 64, LD = D + 4;
constexpr float SCALE = 0.125f;
__global__ __launch_bounds__(256, 3)
void fa_fp32(const float* __restrict__ Q, const float* __restrict__ K,
             const float* __restrict__ V, const int* __restrict__ M,
             float* __restrict__ Out)
{
    __shared__ float Qs[QT][LD];
    __shared__ float Vs[KT][LD];
    __shared__ float KPs[KT][LD];
    const int tid = threadIdx.x, tx = tid & 15, ty = tid >> 4;
    const int bid = blockIdx.x;
    const int h = bid % H, b = (bid / H) % B, qt = bid / (H * B);
    const int q0 = qt * QT;
    {
        const int col = tx * 4;
#pragma unroll
        for (int i = 0; i < 4; ++i) {
            const int row = ty + i * 16;
            *(float4*)&Qs[row][col] = *(const float4*)&Q[((size_t)(b * S + q0 + row)) * E + h * D + col];
        }
    }
    const int qr0 = ty * 4, d0 = tx * 4;
    float acc[4][4] = {};
    float m_i[4], l_i[4];
#pragma unroll
    for (int j = 0; j < 4; ++j) { m_i[j] = -INFINITY; l_i[j] = 0.0f; }
    for (int kt = 0; kt < S; kt += KT) {
        __syncthreads();
        {
            const int col = tx * 4;
#pragma unroll
            for (int i = 0; i < 4; ++i) {
                const int row = ty + i * 16;
                const size_t g = ((size_t)(b * S + kt + row)) * E + h * D + col;
                *(float4*)&KPs[row][col] = *(const float4*)&K[g];
                *(float4*)&Vs[row][col] = *(const float4*)&V[g];
            }
        }
        __syncthreads();
        float s[4][4] = {};
#pragma unroll
        for (int d = 0; d < D; d += 4) {
            float4 a[4], bb[4];
#pragma unroll
            for (int j = 0; j < 4; ++j) a[j] = *(const float4*)&Qs[qr0 + j][d];
#pragma unroll
            for (int i = 0; i < 4; ++i) bb[i] = *(const float4*)&KPs[tx + 16 * i][d];
#pragma unroll
            for (int j = 0; j < 4; ++j)
#pragma unroll
                for (int i = 0; i < 4; ++i)
                    s[j][i] += a[j].x * bb[i].x + a[j].y * bb[i].y + a[j].z * bb[i].z + a[j].w * bb[i].w;
        }
#pragma unroll
        for (int j = 0; j < 4; ++j) {
            const int* mrow = &M[((size_t)b * S + (q0 + qr0 + j)) * S + kt];
#pragma unroll
            for (int i = 0; i < 4; ++i) {
                const int mk = mrow[tx + 16 * i];
                s[j][i] = mk ? s[j][i] * SCALE : NEGF;
            }
        }
#pragma unroll
        for (int j = 0; j < 4; ++j) {
            float tm = fmaxf(fmaxf(s[j][0], s[j][1]), fmaxf(s[j][2], s[j][3]));
#pragma unroll
            for (int off = 8; off; off >>= 1) tm = fmaxf(tm, __shfl_xor(tm, off, 16));
            const float nm = fmaxf(m_i[j], tm);
            const float alpha = __expf(m_i[j] - nm);
            m_i[j] = nm;
            float rs = 0.0f;
#pragma unroll
            for (int i = 0; i < 4; ++i) { const float p = __expf(s[j][i] - nm); s[j][i] = p; rs += p; }
#pragma unroll
            for (int off = 8; off; off >>= 1) rs += __shfl_xor(rs, off, 16);
            l_i[j] = l_i[j] * alpha + rs;
#pragma unroll
            for (int dd = 0; dd < 4; ++dd) acc[j][dd] *= alpha;
        }
        __syncthreads();
#pragma unroll
        for (int j = 0; j < 4; ++j)
#pragma unroll
            for (int i = 0; i < 4; ++i) KPs[qr0 + j][tx + 16 * i] = s[j][i];
        __syncthreads();
#pragma unroll 4
        for (int kk = 0; kk < KT; kk += 4) {
            float4 p[4], vv[4];
#pragma unroll
            for (int j = 0; j < 4; ++j) p[j] = *(const float4*)&KPs[qr0 + j][kk];
#pragma unroll
            for (int u = 0; u < 4; ++u) vv[u] = *(const float4*)&Vs[kk + u][d0];
#pragma unroll
            for (int j = 0; j < 4; ++j) {
                acc[j][0] += p[j].x * vv[0].x + p[j].y * vv[1].x + p[j].z * vv[2].x + p[j].w * vv[3].x;
                acc[j][1] += p[j].x * vv[0].y + p[j].y * vv[1].y + p[j].z * vv[2].y + p[j].w * vv[3].y;
                acc[j][2] += p[j].x * vv[0].z + p[j].y * vv[1].z + p[j].z * vv[2].z + p[j].w * vv[3].z;
                acc[j][3] += p[j].x * vv[0].w + p[j].y * vv[1].w + p[j].z * vv[2].w + p[j].w * vv[3].w;
            }
        }
    }
#pragma unroll
    for (int j = 0; j < 4; ++j) {
        const float iv = 1.0f / l_i[j];
        float4 r;
        r.x = acc[j][0] * iv; r.y = acc[j][1] * iv; r.z = acc[j][2] * iv; r.w = acc[j][3] * iv;
        *(float4*)&Out[((size_t)(b * S + q0 + qr0 + j)) * E + h * D + d0] = r;
    }
}

extern "C" void kernel_launch(void* const* d_in, const int* in_sizes, int n_in,
                              void* d_out, int out_size, void* d_ws, size_t ws_size,
                              hipStream_t stream) {
    (void)in_sizes; (void)n_in; (void)out_size;
    const float* q = (const float*)d_in[0];
    const float* k = (const float*)d_in[1];
    const float* v = (const float*)d_in[2];
    const int*   m = (const int*)d_in[3];
    float* out = (float*)d_out;

    if (ws_size >= WS_NEED) {
        char* ws = (char*)d_ws;
        cvt_qk<<<2048, 256, 0, stream>>>(q, ws + WS_Q, 0.125f);   // scale folded into Q
        cvt_qk<<<2048, 256, 0, stream>>>(k, ws + WS_K, 1.0f);
        vtrans<<<2048, 256, 0, stream>>>(v, ws + WS_VT);
        maskbits<<<8192, 256, 0, stream>>>(m, (unsigned long long*)(ws + WS_MB));
        fa_mfma<<<512, 256, 0, stream>>>(ws, (const unsigned long long*)(ws + WS_MB), out);
    } else {
        fa_fp32<<<B * H * (S / QT), 256, 0, stream>>>(q, k, v, m, out);
    }
}